// Round 6
// baseline (116.354 us; speedup 1.0000x reference)
//
#include <hip/hip_runtime.h>

#define NS 25
#define NQ 200
#define FG 16
#define FL 64
#define FTOT 80
#define D 512
#define WAY 5
#define MROWS 2000    // 25*80 support rows
#define MPAD 2048     // padded to 16 tiles of 128
#define NROWS 16000   // 200*80 query rows

typedef unsigned char u8;
typedef __attribute__((ext_vector_type(4))) float floatx4;
typedef __attribute__((ext_vector_type(4))) int intx4;
typedef __attribute__((ext_vector_type(8))) int intx8;

__device__ inline void gload_lds16(const void* g, void* l) {
    __builtin_amdgcn_global_load_lds(
        (const __attribute__((address_space(1))) unsigned int*)g,
        (__attribute__((address_space(3))) unsigned int*)l, 16, 0, 0);
}

// 4 rows per wave, vectorized loads + interleaved reduce chains (r4 version).
// Block 1125: zero Sn pad rows (2000..2047) + zero out[] + per-class 1/count.
__global__ __launch_bounds__(256) void normalize_kernel(
        const float* __restrict__ sg, const float* __restrict__ sl,
        const float* __restrict__ qg, const float* __restrict__ ql,
        u8* __restrict__ Sn, u8* __restrict__ Qn,
        const int* __restrict__ labels,
        float* __restrict__ out, float* __restrict__ rcnt) {
    if (blockIdx.x == 1125) {
        intx4 z = {0, 0, 0, 0};
        intx4* pad = (intx4*)(Sn + (size_t)MROWS * D);   // 48 rows * 512 B = 1536 intx4
        for (int i = threadIdx.x; i < (MPAD - MROWS) * D / 16; i += 256) pad[i] = z;
        for (int i = threadIdx.x; i < NQ * WAY; i += 256) out[i] = 0.f;
        if (threadIdx.x == 0) {
            int counts[WAY] = {0, 0, 0, 0, 0};
            for (int s = 0; s < NS; ++s) counts[labels[s]]++;
            for (int c = 0; c < WAY; ++c) rcnt[c] = 1.0f / (float)(counts[c] ? counts[c] : 1);
        }
        return;
    }
    const int wv = (blockIdx.x * blockDim.x + threadIdx.x) >> 6;   // 0..4499
    const int lane = threadIdx.x & 63;
    const int row0 = wv * 4;

    const float* srcs[4];
    u8* dsts[4];
    #pragma unroll
    for (int k = 0; k < 4; ++k) {
        const int row = row0 + k;
        if (row < MROWS) {
            const int s = row / FTOT, f = row % FTOT;
            srcs[k] = (f < FG) ? sg + (size_t)(s * FG + f) * D
                               : sl + (size_t)(s * FL + (f - FG)) * D;
            dsts[k] = Sn + (size_t)row * D;
        } else {
            const int r = row - MROWS;
            const int q = r / FTOT, f = r % FTOT;
            srcs[k] = (f < FG) ? qg + (size_t)(q * FG + f) * D
                               : ql + (size_t)(q * FL + (f - FG)) * D;
            dsts[k] = Qn + (size_t)r * D;
        }
    }

    float4 va[4], vb[4];
    #pragma unroll
    for (int k = 0; k < 4; ++k) {
        va[k] = ((const float4*)srcs[k])[2 * lane];
        vb[k] = ((const float4*)srcs[k])[2 * lane + 1];
    }

    float ss[4];
    #pragma unroll
    for (int k = 0; k < 4; ++k)
        ss[k] = va[k].x*va[k].x + va[k].y*va[k].y + va[k].z*va[k].z + va[k].w*va[k].w
              + vb[k].x*vb[k].x + vb[k].y*vb[k].y + vb[k].z*vb[k].z + vb[k].w*vb[k].w;

    #pragma unroll
    for (int off = 32; off > 0; off >>= 1) {
        #pragma unroll
        for (int k = 0; k < 4; ++k) ss[k] += __shfl_xor(ss[k], off, 64);
    }

    #pragma unroll
    for (int k = 0; k < 4; ++k) {
        const float scale = 1.0f / fmaxf(sqrtf(ss[k]), 1e-12f);
        int w0 = __builtin_amdgcn_cvt_pk_fp8_f32(va[k].x * scale, va[k].y * scale, 0, false);
        w0     = __builtin_amdgcn_cvt_pk_fp8_f32(va[k].z * scale, va[k].w * scale, w0, true);
        int w1 = __builtin_amdgcn_cvt_pk_fp8_f32(vb[k].x * scale, vb[k].y * scale, 0, false);
        w1     = __builtin_amdgcn_cvt_pk_fp8_f32(vb[k].z * scale, vb[k].w * scale, w1, true);
        ((int2*)dsts[k])[lane] = make_int2(w0, w1);
    }
}

// 128x128-tile fp8 NT GEMM, MX-scaled K=128 (m148 structure). r5 kernel with
// ONE change: the `union frag` (intx8/intx4[2] type-pun) is replaced by
// __builtin_shufflevector. r3's counters (VGPR_Count=84 + 34 MB WRITE_SIZE)
// show the union forced fragments into scratch (alloca) -- an allocation
// that LOW with that much scratch traffic is alloca, not register pressure.
// shufflevector is a pure SSA concat of the two ds_read_b128 results: the
// operands stay in VGPRs. Expected ~130 VGPR, no scratch.
// Everything else r5-verbatim (passed, absmax 64.0): lockstep 2-barrier,
// gload_lds16 staging with XOR swizzle, unit e8m0 scales (bit-identical
// math to non-scaled fp8 at 2.27x rate), XCD band swizzle, bucketed
// epilogue over the 80-row group boundaries.
__global__ __launch_bounds__(256, 3) void gemm_kernel(const u8* __restrict__ Sn,
                                                      const u8* __restrict__ Qn,
                                                      const int* __restrict__ labels,
                                                      const float* __restrict__ rcnt,
                                                      float* __restrict__ out) {
    __shared__ __align__(16) u8 As[128][128];   // 16B chunk c holds global chunk c^((r>>1)&7)
    __shared__ __align__(16) u8 Bs[128][128];

    // bijective XCD band map: t=(pos<<3)|xcd ; bx=xcd*16+(pos&15), by=pos>>4
    const int t = blockIdx.x;                  // 0..2047
    const int pos = t >> 3;
    const int bx = (t & 7) * 16 + (pos & 15);  // 0..127 (query tile)
    const int by = pos >> 4;                   // 0..15  (support tile)
    if (bx >= 125) return;                     // 48 idle slots

    const int tid = threadIdx.x;
    const int lane = tid & 63;
    const int w = tid >> 6;
    const int lm = lane & 15;
    const int lq = lane >> 4;
    const int wr = w >> 1;              // which 64-row half (support)
    const int wc = w & 1;               // which 64-col half (query)

    floatx4 acc[4][4];
    #pragma unroll
    for (int i = 0; i < 4; ++i)
        #pragma unroll
        for (int j = 0; j < 4; ++j) acc[i][j] = (floatx4){0.f, 0.f, 0.f, 0.f};

    const u8* Sbase = Sn + (size_t)by * 128 * D;
    const u8* Qbase = Qn + (size_t)bx * 128 * D;

    // staging: waves 0,1 -> A; waves 2,3 -> B. 16 slabs of 8 rows (1 KB each).
    const u8* gsrc = (w < 2) ? Sbase : Qbase;
    u8* ldst = (w < 2) ? (u8*)As : (u8*)Bs;
    const int sl0 = (w & 1) * 8;
    const int grow = lane >> 3;         // row within 8-row slab
    const int gc = lane & 7;            // 16B slot-chunk within 128B row

    // lane's 32B = global k-chunks 2lq,2lq+1, stored at (2lq)^s and
    // ((2lq)^s)^1 (adjacent 16B), s=(r>>1)&7
    int aoff[4], boff[4];
    #pragma unroll
    for (int i = 0; i < 4; ++i) {
        const int ra = wr * 64 + i * 16 + lm;
        aoff[i] = ra * 128 + (((2 * lq) ^ ((ra >> 1) & 7)) * 16);
        const int rb = wc * 64 + i * 16 + lm;
        boff[i] = rb * 128 + (((2 * lq) ^ ((rb >> 1) & 7)) * 16);
    }

    #pragma unroll 1
    for (int kc = 0; kc < 4; ++kc) {
        const int k0 = kc * 128;
        __syncthreads();                // prev chunk's readers done
        #pragma unroll
        for (int u = 0; u < 8; ++u) {
            const int sl = sl0 + u;
            const int r = sl * 8 + grow;
            const int cp = gc ^ ((r >> 1) & 7);
            gload_lds16(gsrc + (size_t)r * D + k0 + cp * 16, ldst + sl * 1024);
        }
        __syncthreads();                // drains vmcnt (global_load_lds) too

        intx8 af[4];
        #pragma unroll
        for (int i = 0; i < 4; ++i) {
            const intx4 lo = *(const intx4*)((const u8*)As + aoff[i]);
            const intx4 hi = *(const intx4*)((const u8*)As + (aoff[i] ^ 16));
            af[i] = __builtin_shufflevector(lo, hi, 0, 1, 2, 3, 4, 5, 6, 7);
        }
        #pragma unroll
        for (int j = 0; j < 4; ++j) {
            const intx4 lo = *(const intx4*)((const u8*)Bs + boff[j]);
            const intx4 hi = *(const intx4*)((const u8*)Bs + (boff[j] ^ 16));
            const intx8 bf = __builtin_shufflevector(lo, hi, 0, 1, 2, 3, 4, 5, 6, 7);
            #pragma unroll
            for (int i = 0; i < 4; ++i)
                acc[i][j] = __builtin_amdgcn_mfma_scale_f32_16x16x128_f8f6f4(
                    af[i], bf, acc[i][j], 0, 0,
                    0, 0x7F7F7F7F, 0, 0x7F7F7F7F);
        }
    }

    // ---- bucketed epilogue: sum (1-sim)^2 into <=2x2 (s,q) cells ----
    const int R0 = by * 128 + wr * 64;  // global support row base
    const int C0 = bx * 128 + wc * 64;  // global query row base
    const int s0 = R0 / 80;
    const int q0 = C0 / 80;
    int rsplit = (s0 + 1) * 80 - R0; if (rsplit > 64) rsplit = 64;
    int csplit = (q0 + 1) * 80 - C0; if (csplit > 64) csplit = 64;

    float l00 = 0.f, l01 = 0.f, l10 = 0.f, l11 = 0.f;
    const int rowb = (lane >> 4) * 4;   // C/D: row dim (support)
    const int colb = lane & 15;         // C/D: col dim (query)
    #pragma unroll
    for (int i = 0; i < 4; ++i)
        #pragma unroll
        for (int j = 0; j < 4; ++j) {
            const int lcol = j * 16 + colb;
            #pragma unroll
            for (int r = 0; r < 4; ++r) {
                const int lrow = i * 16 + rowb + r;
                const float d = 1.0f - acc[i][j][r];
                const float dd = d * d;
                if (lrow < rsplit) { if (lcol < csplit) l00 += dd; else l01 += dd; }
                else               { if (lcol < csplit) l10 += dd; else l11 += dd; }
            }
        }

    #pragma unroll
    for (int off = 32; off > 0; off >>= 1) {
        l00 += __shfl_down(l00, off, 64);
        l01 += __shfl_down(l01, off, 64);
        l10 += __shfl_down(l10, off, 64);
        l11 += __shfl_down(l11, off, 64);
    }

    if (lane == 0) {
        #pragma unroll
        for (int si = 0; si < 2; ++si) {
            const int s = s0 + si;
            if (si == 1 && rsplit >= 64) continue;   // no second row-group
            if (s >= NS) continue;                   // pad rows
            const int c = labels[s];
            const float rc = -2.0f * rcnt[c];
            #pragma unroll
            for (int qi = 0; qi < 2; ++qi) {
                if (qi == 1 && csplit >= 64) continue;
                const int q = q0 + qi;
                const float v = si ? (qi ? l11 : l10) : (qi ? l01 : l00);
                atomicAdd(&out[q * WAY + c], v * rc);
            }
        }
    }
}

extern "C" void kernel_launch(void* const* d_in, const int* in_sizes, int n_in,
                              void* d_out, int out_size, void* d_ws, size_t ws_size,
                              hipStream_t stream) {
    const float* sg = (const float*)d_in[0];
    const float* sl = (const float*)d_in[1];
    const int* labels = (const int*)d_in[2];
    const float* qg = (const float*)d_in[3];
    const float* ql = (const float*)d_in[4];
    float* out = (float*)d_out;

    u8* Sn = (u8*)d_ws;                          // 2048*512 fp8 (padded)
    u8* Qn = Sn + (size_t)MPAD * D;              // 16000*512 fp8
    float* rcnt = (float*)(Qn + (size_t)NROWS * D);

    normalize_kernel<<<1126, 256, 0, stream>>>(sg, sl, qg, ql, Sn, Qn, labels, out, rcnt);
    gemm_kernel<<<2048, 256, 0, stream>>>(Sn, Qn, labels, rcnt, out);
}

// Round 7
// 112.999 us; speedup vs baseline: 1.0297x; 1.0297x over previous
//
#include <hip/hip_runtime.h>

#define NS 25
#define NQ 200
#define FG 16
#define FL 64
#define FTOT 80
#define D 512
#define WAY 5
#define MROWS 2000    // 25*80 support rows
#define MPAD 2080     // padded to 13 tiles of 160
#define NROWS 16000   // 200*80 query rows

typedef unsigned char u8;
typedef __attribute__((ext_vector_type(4))) float floatx4;
typedef __attribute__((ext_vector_type(4))) int intx4;

__device__ inline void gload_lds16(const void* g, void* l) {
    __builtin_amdgcn_global_load_lds(
        (const __attribute__((address_space(1))) unsigned int*)g,
        (__attribute__((address_space(3))) unsigned int*)l, 16, 0, 0);
}

// 4 rows per wave, vectorized loads + interleaved reduce chains (r4 version;
// measured ~9 us = 81% of HBM roofline for 46 MB moved -- done).
// Block 1125: zero Sn pad rows (2000..2079) + zero out[] + per-class 1/count.
__global__ __launch_bounds__(256) void normalize_kernel(
        const float* __restrict__ sg, const float* __restrict__ sl,
        const float* __restrict__ qg, const float* __restrict__ ql,
        u8* __restrict__ Sn, u8* __restrict__ Qn,
        const int* __restrict__ labels,
        float* __restrict__ out, float* __restrict__ rcnt) {
    if (blockIdx.x == 1125) {
        intx4 z = {0, 0, 0, 0};
        intx4* pad = (intx4*)(Sn + (size_t)MROWS * D);   // 80 rows * 512 B = 2560 intx4
        for (int i = threadIdx.x; i < (MPAD - MROWS) * D / 16; i += 256) pad[i] = z;
        for (int i = threadIdx.x; i < NQ * WAY; i += 256) out[i] = 0.f;
        if (threadIdx.x == 0) {
            int counts[WAY] = {0, 0, 0, 0, 0};
            for (int s = 0; s < NS; ++s) counts[labels[s]]++;
            for (int c = 0; c < WAY; ++c) rcnt[c] = 1.0f / (float)(counts[c] ? counts[c] : 1);
        }
        return;
    }
    const int wv = (blockIdx.x * blockDim.x + threadIdx.x) >> 6;   // 0..4499
    const int lane = threadIdx.x & 63;
    const int row0 = wv * 4;

    const float* srcs[4];
    u8* dsts[4];
    #pragma unroll
    for (int k = 0; k < 4; ++k) {
        const int row = row0 + k;
        if (row < MROWS) {
            const int s = row / FTOT, f = row % FTOT;
            srcs[k] = (f < FG) ? sg + (size_t)(s * FG + f) * D
                               : sl + (size_t)(s * FL + (f - FG)) * D;
            dsts[k] = Sn + (size_t)row * D;
        } else {
            const int r = row - MROWS;
            const int q = r / FTOT, f = r % FTOT;
            srcs[k] = (f < FG) ? qg + (size_t)(q * FG + f) * D
                               : ql + (size_t)(q * FL + (f - FG)) * D;
            dsts[k] = Qn + (size_t)r * D;
        }
    }

    float4 va[4], vb[4];
    #pragma unroll
    for (int k = 0; k < 4; ++k) {
        va[k] = ((const float4*)srcs[k])[2 * lane];
        vb[k] = ((const float4*)srcs[k])[2 * lane + 1];
    }

    float ss[4];
    #pragma unroll
    for (int k = 0; k < 4; ++k)
        ss[k] = va[k].x*va[k].x + va[k].y*va[k].y + va[k].z*va[k].z + va[k].w*va[k].w
              + vb[k].x*vb[k].x + vb[k].y*vb[k].y + vb[k].z*vb[k].z + vb[k].w*vb[k].w;

    #pragma unroll
    for (int off = 32; off > 0; off >>= 1) {
        #pragma unroll
        for (int k = 0; k < 4; ++k) ss[k] += __shfl_xor(ss[k], off, 64);
    }

    #pragma unroll
    for (int k = 0; k < 4; ++k) {
        const float scale = 1.0f / fmaxf(sqrtf(ss[k]), 1e-12f);
        int w0 = __builtin_amdgcn_cvt_pk_fp8_f32(va[k].x * scale, va[k].y * scale, 0, false);
        w0     = __builtin_amdgcn_cvt_pk_fp8_f32(va[k].z * scale, va[k].w * scale, w0, true);
        int w1 = __builtin_amdgcn_cvt_pk_fp8_f32(vb[k].x * scale, vb[k].y * scale, 0, false);
        w1     = __builtin_amdgcn_cvt_pk_fp8_f32(vb[k].z * scale, vb[k].w * scale, w1, true);
        ((int2*)dsts[k])[lane] = make_int2(w0, w1);
    }
}

// 160x160-tile NON-SCALED fp8 NT GEMM (r0/r4-proven math + addressing,
// measured ~32 us twice), restructured as T3 minimal 2-phase:
//   stage(buf0); barrier;
//   for kc: [issue stage(buf^1, kc+1)] -> ds_read+MFMA from buf -> barrier
// Double-buffered LDS (2 x 40 KB = 80 KB -> 2 blocks/CU). The per-chunk
// vmcnt(0) drain at the barrier now lands AFTER ~1960 cyc of MFMA instead
// of before it (r0's lockstep exposed ~600-900 cyc of load latency per
// chunk, only partly hidden by the 3rd resident block).
// MX is abandoned: 4 structures all measured 38-53 us (880 TF) vs
// non-scaled's 32 us (1070 TF) -- stall-bound, compute window too short.
// Epilogue: sum (1-sim)^2 -> fused class-mean logits via one atomic per wave.
__global__ __launch_bounds__(256, 2) void gemm_kernel(const u8* __restrict__ Sn,
                                                      const u8* __restrict__ Qn,
                                                      const int* __restrict__ labels,
                                                      const float* __restrict__ rcnt,
                                                      float* __restrict__ out) {
    __shared__ __align__(16) u8 As[2][160][128];  // 16B chunk c holds global chunk c^((r>>1)&7)
    __shared__ __align__(16) u8 Bs[2][160][128];

    const int bx = blockIdx.x;          // 0..99  (query groups, 2 per block)
    const int by = blockIdx.y;          // 0..12  (support groups, 2 per block)
    const int tid = threadIdx.x;
    const int lane = tid & 63;
    const int w = tid >> 6;
    const int lm = lane & 15;
    const int lq = lane >> 4;
    const int wr = w >> 1;              // which 80-row half
    const int wc = w & 1;               // which 80-col half

    floatx4 acc[5][5];
    #pragma unroll
    for (int i = 0; i < 5; ++i)
        #pragma unroll
        for (int j = 0; j < 5; ++j) acc[i][j] = (floatx4){0.f, 0.f, 0.f, 0.f};

    const u8* Sbase = Sn + (size_t)by * 160 * D;
    const u8* Qbase = Qn + (size_t)bx * 160 * D;

    // staging: waves 0,1 -> A; waves 2,3 -> B. 20 slabs of 8 rows (1 KB each).
    const u8* gsrc = (w < 2) ? Sbase : Qbase;
    u8* ldstBase = (w < 2) ? &As[0][0][0] : &Bs[0][0][0];
    const int sl0 = (w & 1) * 10;
    const int grow = lane >> 3;         // row within 8-row slab
    const int gc = lane & 7;            // 16B slot-chunk within 128B row

    // ---- prologue: stage chunk 0 into buffer 0 ----
    #pragma unroll
    for (int t = 0; t < 10; ++t) {
        const int sl = sl0 + t;
        const int r = sl * 8 + grow;
        const int cp = gc ^ ((r >> 1) & 7);
        gload_lds16(gsrc + (size_t)r * D + cp * 16, ldstBase + sl * 1024);
    }
    __syncthreads();                    // drains vmcnt: buffer 0 ready

    #pragma unroll 1
    for (int kc = 0; kc < 4; ++kc) {
        // 1) issue next chunk's staging into the other buffer (async, in
        //    flight under this chunk's ds_read + MFMA)
        if (kc < 3) {
            const int k0 = (kc + 1) * 128;
            u8* dstb = ldstBase + ((kc + 1) & 1) * 20480;
            #pragma unroll
            for (int t = 0; t < 10; ++t) {
                const int sl = sl0 + t;
                const int r = sl * 8 + grow;
                const int cp = gc ^ ((r >> 1) & 7);
                gload_lds16(gsrc + (size_t)r * D + k0 + cp * 16, dstb + sl * 1024);
            }
        }
        // 2) compute current chunk (r0-verbatim fragment math)
        const u8* Acur = &As[kc & 1][0][0];
        const u8* Bcur = &Bs[kc & 1][0][0];
        #pragma unroll
        for (int ks = 0; ks < 4; ++ks) {
            long long a[5], b[5];
            #pragma unroll
            for (int i = 0; i < 5; ++i) {
                const int r = wr * 80 + i * 16 + lm;
                const int c = (ks * 2 + (lq >> 1)) ^ ((r >> 1) & 7);
                a[i] = *(const long long*)(Acur + r * 128 + c * 16 + (lq & 1) * 8);
            }
            #pragma unroll
            for (int j = 0; j < 5; ++j) {
                const int r = wc * 80 + j * 16 + lm;
                const int c = (ks * 2 + (lq >> 1)) ^ ((r >> 1) & 7);
                b[j] = *(const long long*)(Bcur + r * 128 + c * 16 + (lq & 1) * 8);
            }
            #pragma unroll
            for (int i = 0; i < 5; ++i)
                #pragma unroll
                for (int j = 0; j < 5; ++j)
                    acc[i][j] = __builtin_amdgcn_mfma_f32_16x16x32_fp8_fp8(a[i], b[j], acc[i][j], 0, 0, 0);
        }
        __syncthreads();                // drains vmcnt: next buffer ready;
                                        // also orders readers before overwrite
    }

    // Epilogue: sum (1-sim)^2 over the wave's 80x80 block, fuse class-mean.
    float local = 0.f;
    #pragma unroll
    for (int i = 0; i < 5; ++i)
        #pragma unroll
        for (int j = 0; j < 5; ++j)
            #pragma unroll
            for (int r = 0; r < 4; ++r) {
                const float d = 1.0f - acc[i][j][r];
                local = fmaf(d, d, local);
            }
    #pragma unroll
    for (int off = 32; off > 0; off >>= 1) local += __shfl_down(local, off, 64);

    const int sIdx = by * 2 + wr;       // 25 = pad group, dropped
    const int qIdx = bx * 2 + wc;
    if (lane == 0 && sIdx < NS) {
        const int c = labels[sIdx];
        atomicAdd(&out[qIdx * WAY + c], -2.0f * local * rcnt[c]);
    }
}

extern "C" void kernel_launch(void* const* d_in, const int* in_sizes, int n_in,
                              void* d_out, int out_size, void* d_ws, size_t ws_size,
                              hipStream_t stream) {
    const float* sg = (const float*)d_in[0];
    const float* sl = (const float*)d_in[1];
    const int* labels = (const int*)d_in[2];
    const float* qg = (const float*)d_in[3];
    const float* ql = (const float*)d_in[4];
    float* out = (float*)d_out;

    u8* Sn = (u8*)d_ws;                          // 2080*512 fp8 (padded)
    u8* Qn = Sn + (size_t)MPAD * D;              // 16000*512 fp8
    float* rcnt = (float*)(Qn + (size_t)NROWS * D);

    normalize_kernel<<<1126, 256, 0, stream>>>(sg, sl, qg, ql, Sn, Qn, labels, out, rcnt);
    dim3 g2(100, 13);
    gemm_kernel<<<g2, 256, 0, stream>>>(Sn, Qn, labels, rcnt, out);
}